// Round 2
// baseline (480.170 us; speedup 1.0000x reference)
//
#include <hip/hip_runtime.h>

#define NNODES 1700
#define CDIM   256

typedef __attribute__((ext_vector_type(8))) short bf16x8;
typedef __attribute__((ext_vector_type(4))) float f32x4;

__device__ inline float bf2f(unsigned h) { return __uint_as_float(h << 16); }
__device__ inline unsigned short f2bf(float f) {
  unsigned u = __float_as_uint(f);
  u = (u + 0x7FFFu + ((u >> 16) & 1u)) >> 16;  // RNE
  return (unsigned short)u;
}

__device__ inline void async_copy16(const void* gsrc, void* ldst) {
  __builtin_amdgcn_global_load_lds(
      (const __attribute__((address_space(1))) unsigned int*)gsrc,
      (__attribute__((address_space(3))) unsigned int*)ldst,
      16, 0, 0);
}

// ---------------- graph preprocessing ----------------

__global__ void zero_kernel(int* p, int n) {
  int i = blockIdx.x * blockDim.x + threadIdx.x;
  if (i < n) p[i] = 0;
}

// edge_index layout [2, E] row-major: sources [0..E), destinations [E..2E)
__global__ void count_kernel(const int* __restrict__ ei, int E, int* __restrict__ cnt) {
  int i = blockIdx.x * blockDim.x + threadIdx.x;
  if (i < E) atomicAdd(&cnt[ei[E + i]], 1);
}

__global__ void dinv_kernel(const int* __restrict__ cnt, float* __restrict__ dinv, int n) {
  int i = blockIdx.x * blockDim.x + threadIdx.x;
  if (i < n) dinv[i] = rsqrtf((float)(cnt[i] + 1));  // +1 self-loop; deg >= 1
}

// exclusive scan of (cnt[i]+1) over N=1700 -> off[0..N]; single block, 1024 thr, 2048 slots
__global__ __launch_bounds__(1024) void scan_kernel(const int* __restrict__ cnt, int n,
                                                    int* __restrict__ off) {
  __shared__ int s[2048];
  int t = threadIdx.x;
  for (int i = t; i < 2048; i += 1024) s[i] = (i < n) ? (cnt[i] + 1) : 0;
  for (int d = 1; d < 2048; d <<= 1) {
    __syncthreads();
    int idx = (t + 1) * (d << 1) - 1;
    if (idx < 2048) s[idx] += s[idx - d];
  }
  __syncthreads();
  if (t == 0) s[2047] = 0;
  for (int d = 1024; d >= 1; d >>= 1) {
    __syncthreads();
    int idx = (t + 1) * (d << 1) - 1;
    if (idx < 2048) { int tmp = s[idx - d]; s[idx - d] = s[idx]; s[idx] += tmp; }
  }
  __syncthreads();
  for (int i = t; i <= n; i += 1024) off[i] = s[i];
}

__global__ void fill_kernel(const int* __restrict__ ei, int E, int n,
                            const float* __restrict__ dinv, const int* __restrict__ off,
                            int* __restrict__ cursor, int* __restrict__ srcv,
                            float* __restrict__ wv) {
  int i = blockIdx.x * blockDim.x + threadIdx.x;
  if (i >= E + n) return;
  int s, d;
  if (i < E) { s = ei[i]; d = ei[E + i]; } else { s = d = i - E; }
  float w = dinv[s] * dinv[d];
  int p = atomicAdd(&cursor[d], 1);
  int idx = off[d] + p;
  srcv[idx] = s;
  wv[idx] = w;
}

// W f32 [k][n] row-major -> Wt bf16 [n][k]
__global__ void transpose_kernel(const float* __restrict__ W,
                                 unsigned short* __restrict__ Wt) {
  int i = blockIdx.x * 256 + threadIdx.x;  // 65536 elems
  int k = i >> 8, n = i & 255;
  Wt[n * 256 + k] = f2bf(W[i]);
}

// ---------------- GEMM: H[M][256] = A[M][256] @ W ; Wt is bf16 W^T [n][k] ------------------
// 128x128 tile, 4 waves, MFMA 16x16x32 bf16, fp32 accum, bf16 out.
// AF32: A is f32, staged via per-lane loads + RNE convert. else: A bf16, global_load_lds.

template <bool AF32>
__global__ __launch_bounds__(256) void gemm128(const void* __restrict__ Ap,
                                               const unsigned short* __restrict__ Wt,
                                               unsigned short* __restrict__ H) {
  __shared__ __align__(16) unsigned short As[128 * 32];
  __shared__ __align__(16) unsigned short Bs[128 * 32];
  const int m0 = blockIdx.x * 128;
  const int n0 = blockIdx.y * 128;
  const int t = threadIdx.x;
  const int lane = t & 63;
  const int w = t >> 6;
  const int wm = (w & 1) * 64;
  const int wn = (w >> 1) * 64;
  const int lr = lane & 15;        // row (A) / col (B) within 16-tile
  const int lk = (lane >> 4) * 8;  // k offset within BK=32

  f32x4 acc[4][4] = {};

  const int q0 = t;          // 16B-chunk id: row=q>>2, k-halfword-off=(q&3)*8
  const int q1 = t + 256;

  for (int k0 = 0; k0 < 256; k0 += 32) {
    if (AF32) {
      const float* A = (const float*)Ap;
      const int row = t >> 1, kh = (t & 1) * 16;  // 128 rows x 2 half-rows of 16 k
      const float* g = A + (size_t)(m0 + row) * CDIM + k0 + kh;
      float4 f0 = *(const float4*)(g + 0);
      float4 f1 = *(const float4*)(g + 4);
      float4 f2 = *(const float4*)(g + 8);
      float4 f3 = *(const float4*)(g + 12);
      unsigned short* dst = &As[row * 32 + kh];
      bf16x8 p0, p1;
      p0[0] = (short)f2bf(f0.x); p0[1] = (short)f2bf(f0.y);
      p0[2] = (short)f2bf(f0.z); p0[3] = (short)f2bf(f0.w);
      p0[4] = (short)f2bf(f1.x); p0[5] = (short)f2bf(f1.y);
      p0[6] = (short)f2bf(f1.z); p0[7] = (short)f2bf(f1.w);
      p1[0] = (short)f2bf(f2.x); p1[1] = (short)f2bf(f2.y);
      p1[2] = (short)f2bf(f2.z); p1[3] = (short)f2bf(f2.w);
      p1[4] = (short)f2bf(f3.x); p1[5] = (short)f2bf(f3.y);
      p1[6] = (short)f2bf(f3.z); p1[7] = (short)f2bf(f3.w);
      *(bf16x8*)(dst) = p0;
      *(bf16x8*)(dst + 8) = p1;
    } else {
      const unsigned short* A = (const unsigned short*)Ap;
      async_copy16(A + (size_t)(m0 + (q0 >> 2)) * CDIM + k0 + (q0 & 3) * 8, As + q0 * 8);
      async_copy16(A + (size_t)(m0 + (q1 >> 2)) * CDIM + k0 + (q1 & 3) * 8, As + q1 * 8);
    }
    async_copy16(Wt + (size_t)(n0 + (q0 >> 2)) * CDIM + k0 + (q0 & 3) * 8, Bs + q0 * 8);
    async_copy16(Wt + (size_t)(n0 + (q1 >> 2)) * CDIM + k0 + (q1 & 3) * 8, Bs + q1 * 8);
    __syncthreads();  // compiler drains vmcnt+lgkm before barrier

    bf16x8 a[4], b[4];
#pragma unroll
    for (int i = 0; i < 4; i++)
      a[i] = *(const bf16x8*)&As[(wm + i * 16 + lr) * 32 + lk];
#pragma unroll
    for (int i = 0; i < 4; i++)
      b[i] = *(const bf16x8*)&Bs[(wn + i * 16 + lr) * 32 + lk];
#pragma unroll
    for (int mi = 0; mi < 4; mi++)
#pragma unroll
      for (int ni = 0; ni < 4; ni++)
        acc[mi][ni] = __builtin_amdgcn_mfma_f32_16x16x32_bf16(a[mi], b[ni], acc[mi][ni], 0, 0, 0);
    __syncthreads();
  }

  const int orow = (lane >> 4) * 4;  // C/D: col=lane&15, row=(lane>>4)*4+r  [m89/m91]
#pragma unroll
  for (int mi = 0; mi < 4; mi++) {
#pragma unroll
    for (int ni = 0; ni < 4; ni++) {
#pragma unroll
      for (int r = 0; r < 4; r++) {
        int gr = m0 + wm + mi * 16 + orow + r;
        int gc = n0 + wn + ni * 16 + lr;
        H[(size_t)gr * CDIM + gc] = f2bf(acc[mi][ni][r]);
      }
    }
  }
}

// ---------------- aggregation: out[b,n,:] = relu(sum_e w_e * H[b,src_e,:] + bias (+resid)) ----
// grid (NNODES, B/4), block 256: 4 batches x 64 threads x 4 channels.
// FINAL: add f32 residual, write f32 out. else: write bf16 out.

template <bool FINAL>
__global__ __launch_bounds__(256) void agg_kernel(const unsigned short* __restrict__ H,
                                                  const int* __restrict__ off,
                                                  const int* __restrict__ srcv,
                                                  const float* __restrict__ wv,
                                                  const float* __restrict__ bias,
                                                  const float* __restrict__ resid,
                                                  void* __restrict__ outp) {
  const int n = blockIdx.x;
  const int b = blockIdx.y * 4 + (threadIdx.x >> 6);
  const int c = (threadIdx.x & 63) * 4;
  const int beg = off[n], end = off[n + 1];

  float a0 = 0.f, a1 = 0.f, a2 = 0.f, a3 = 0.f;
  for (int i = beg; i < end; i++) {
    int s = srcv[i];
    float w = wv[i];
    uint2 v = *(const uint2*)(H + ((size_t)b * NNODES + s) * CDIM + c);
    a0 += w * bf2f(v.x & 0xffffu);
    a1 += w * bf2f(v.x >> 16);
    a2 += w * bf2f(v.y & 0xffffu);
    a3 += w * bf2f(v.y >> 16);
  }
  float4 bv = *(const float4*)(bias + c);
  a0 += bv.x; a1 += bv.y; a2 += bv.z; a3 += bv.w;

  const size_t o = ((size_t)b * NNODES + n) * CDIM + c;
  if (FINAL) {
    float4 rv = *(const float4*)(resid + o);
    a0 += rv.x; a1 += rv.y; a2 += rv.z; a3 += rv.w;
  }
  a0 = fmaxf(a0, 0.f); a1 = fmaxf(a1, 0.f); a2 = fmaxf(a2, 0.f); a3 = fmaxf(a3, 0.f);

  if (FINAL) {
    float4 ov; ov.x = a0; ov.y = a1; ov.z = a2; ov.w = a3;
    *(float4*)((float*)outp + o) = ov;
  } else {
    uint2 ov;
    ov.x = (unsigned)f2bf(a0) | ((unsigned)f2bf(a1) << 16);
    ov.y = (unsigned)f2bf(a2) | ((unsigned)f2bf(a3) << 16);
    *(uint2*)((unsigned short*)outp + o) = ov;
  }
}

// ---------------- launch ----------------

extern "C" void kernel_launch(void* const* d_in, const int* in_sizes, int n_in,
                              void* d_out, int out_size, void* d_ws, size_t ws_size,
                              hipStream_t stream) {
  const float* x  = (const float*)d_in[0];
  const float* W1 = (const float*)d_in[1];
  const float* b1 = (const float*)d_in[2];
  const float* W2 = (const float*)d_in[3];
  const float* b2 = (const float*)d_in[4];
  const float* W3 = (const float*)d_in[5];
  const float* b3 = (const float*)d_in[6];
  const int* esp = (const int*)d_in[7];
  const int* etm = (const int*)d_in[8];

  const int Esp = in_sizes[7] / 2;
  const int Etm = in_sizes[8] / 2;
  const int B = in_sizes[0] / (NNODES * CDIM);
  const int M = B * NNODES;

  char* ws = (char*)d_ws;
  size_t woff = 0;
  auto alloc = [&](size_t bytes) -> void* {
    void* p = ws + woff;
    woff = (woff + bytes + 255) & ~(size_t)255;
    return p;
  };

  unsigned short* H   = (unsigned short*)alloc((size_t)M * CDIM * 2);  // 55.7 MB bf16
  unsigned short* Act = (unsigned short*)alloc((size_t)M * CDIM * 2);  // 55.7 MB bf16
  unsigned short* Wt  = (unsigned short*)alloc((size_t)3 * CDIM * CDIM * 2);
  int* zero_base = (int*)alloc((size_t)4 * NNODES * sizeof(int));
  int* cnt_sp = zero_base;
  int* cur_sp = zero_base + NNODES;
  int* cnt_tm = zero_base + 2 * NNODES;
  int* cur_tm = zero_base + 3 * NNODES;
  int* off_sp = (int*)alloc((NNODES + 1) * sizeof(int));
  int* off_tm = (int*)alloc((NNODES + 1) * sizeof(int));
  float* dinv_sp = (float*)alloc(NNODES * sizeof(float));
  float* dinv_tm = (float*)alloc(NNODES * sizeof(float));
  int*   src_sp = (int*)alloc((size_t)(Esp + NNODES) * sizeof(int));
  float* wgt_sp = (float*)alloc((size_t)(Esp + NNODES) * sizeof(float));
  int*   src_tm = (int*)alloc((size_t)(Etm + NNODES) * sizeof(int));
  float* wgt_tm = (float*)alloc((size_t)(Etm + NNODES) * sizeof(float));

  // graph preprocessing
  zero_kernel<<<(4 * NNODES + 255) / 256, 256, 0, stream>>>(zero_base, 4 * NNODES);
  transpose_kernel<<<256, 256, 0, stream>>>(W1, Wt);
  transpose_kernel<<<256, 256, 0, stream>>>(W2, Wt + CDIM * CDIM);
  transpose_kernel<<<256, 256, 0, stream>>>(W3, Wt + 2 * CDIM * CDIM);
  count_kernel<<<(Esp + 255) / 256, 256, 0, stream>>>(esp, Esp, cnt_sp);
  count_kernel<<<(Etm + 255) / 256, 256, 0, stream>>>(etm, Etm, cnt_tm);
  dinv_kernel<<<(NNODES + 255) / 256, 256, 0, stream>>>(cnt_sp, dinv_sp, NNODES);
  dinv_kernel<<<(NNODES + 255) / 256, 256, 0, stream>>>(cnt_tm, dinv_tm, NNODES);
  scan_kernel<<<1, 1024, 0, stream>>>(cnt_sp, NNODES, off_sp);
  scan_kernel<<<1, 1024, 0, stream>>>(cnt_tm, NNODES, off_tm);
  fill_kernel<<<(Esp + NNODES + 255) / 256, 256, 0, stream>>>(esp, Esp, NNODES, dinv_sp,
                                                              off_sp, cur_sp, src_sp, wgt_sp);
  fill_kernel<<<(Etm + NNODES + 255) / 256, 256, 0, stream>>>(etm, Etm, NNODES, dinv_tm,
                                                              off_tm, cur_tm, src_tm, wgt_tm);

  dim3 ggrid(M / 128, CDIM / 128);
  dim3 agrid(NNODES, B / 4);

  // layer 1 (spatial edges): f32 x -> bf16 H -> bf16 Act
  gemm128<true><<<ggrid, 256, 0, stream>>>(x, Wt, H);
  agg_kernel<false><<<agrid, 256, 0, stream>>>(H, off_sp, src_sp, wgt_sp, b1, nullptr, Act);
  // layer 2 (temporal edges)
  gemm128<false><<<ggrid, 256, 0, stream>>>(Act, Wt + CDIM * CDIM, H);
  agg_kernel<false><<<agrid, 256, 0, stream>>>(H, off_tm, src_tm, wgt_tm, b2, nullptr, Act);
  // layer 3 (spatial edges) + residual + relu -> f32 d_out
  gemm128<false><<<ggrid, 256, 0, stream>>>(Act, Wt + 2 * CDIM * CDIM, H);
  agg_kernel<true><<<agrid, 256, 0, stream>>>(H, off_sp, src_sp, wgt_sp, b3, x, d_out);
}